// Round 1
// baseline (2992.344 us; speedup 1.0000x reference)
//
#include <hip/hip_runtime.h>
#include <hip/hip_bf16.h>

#define DD 2048
#define NF 24
#define NROWS 4096
#define VOCAB_N 32000
#define EPS_F 1.1920929e-07f

typedef __attribute__((ext_vector_type(8))) __bf16 bf16x8;
typedef __attribute__((ext_vector_type(4))) float f32x4;

__device__ __forceinline__ unsigned short f2bf(float f) {
  union { float f; unsigned int u; } v; v.f = f;
  unsigned int r = v.u + 0x7fffu + ((v.u >> 16) & 1u);  // RNE
  return (unsigned short)(r >> 16);
}

__device__ __forceinline__ void gload_lds16(const void* g, void* l) {
  __builtin_amdgcn_global_load_lds(
      (const __attribute__((address_space(1))) void*)g,
      (__attribute__((address_space(3))) void*)l, 16, 0, 0);
}

// ---------------- embedding gather: x[row] = embed[tok[row]] ----------------
__global__ __launch_bounds__(256) void k_gather(const int* __restrict__ tok,
                                                const float* __restrict__ embed,
                                                float* __restrict__ x) {
  const int row = blockIdx.x;
  const int t = tok[row];
  const float4* s = (const float4*)(embed + (size_t)t * DD);
  float4* d = (float4*)(x + (size_t)row * DD);
  d[threadIdx.x] = s[threadIdx.x];
  d[threadIdx.x + 256] = s[threadIdx.x + 256];
}

// ---------------- W reconstruction ----------------
// W_bf16[f][e][d] = scale[f] * (HR[e][d]*PR - HI[e][d]*PI)
//   PR = sum_r kar[f,r,e]*kbr[f,r,d] + kai[f,r,e]*kbi[f,r,d]
//   PI = sum_r kai[f,r,e]*kbr[f,r,d] - kar[f,r,e]*kbi[f,r,d]
// (e = GEMM output col index = reference W's first matrix index)
__global__ __launch_bounds__(256) void k_wrec(
    const float* __restrict__ hr, const float* __restrict__ hi,
    const float* __restrict__ kar, const float* __restrict__ kai,
    const float* __restrict__ kbr, const float* __restrict__ kbi,
    const float* __restrict__ scale, unsigned short* __restrict__ W) {
  __shared__ float HR[64][64], HI[64][64];
  __shared__ float AR[16][64], AI[16][64], BR[16][64], BI[16][64];
  const int e0 = blockIdx.x * 64, d0 = blockIdx.y * 64;
  const int tid = threadIdx.x;
  {
    const int r = tid >> 2, cbase = (tid & 3) * 16;
#pragma unroll
    for (int j = 0; j < 4; ++j) {
      const int c = cbase + j * 4;
      *(float4*)&HR[r][c] = *(const float4*)&hr[(size_t)(e0 + r) * DD + d0 + c];
      *(float4*)&HI[r][c] = *(const float4*)&hi[(size_t)(e0 + r) * DD + d0 + c];
    }
  }
  const int te = tid >> 4, td = tid & 15;
  for (int f = 0; f < NF; ++f) {
    __syncthreads();
    {
      const int r = tid >> 4, c = (tid & 15) * 4;
      const size_t ga = ((size_t)f * 16 + r) * DD;
      *(float4*)&AR[r][c] = *(const float4*)&kar[ga + e0 + c];
      *(float4*)&AI[r][c] = *(const float4*)&kai[ga + e0 + c];
      *(float4*)&BR[r][c] = *(const float4*)&kbr[ga + d0 + c];
      *(float4*)&BI[r][c] = *(const float4*)&kbi[ga + d0 + c];
    }
    __syncthreads();
    float pr[4][4], pi[4][4];
#pragma unroll
    for (int i = 0; i < 4; ++i)
#pragma unroll
      for (int j = 0; j < 4; ++j) { pr[i][j] = 0.f; pi[i][j] = 0.f; }
#pragma unroll 4
    for (int r = 0; r < 16; ++r) {
      float ar[4], ai[4], br[4], bi[4];
      *(float4*)ar = *(const float4*)&AR[r][te * 4];
      *(float4*)ai = *(const float4*)&AI[r][te * 4];
      *(float4*)br = *(const float4*)&BR[r][td * 4];
      *(float4*)bi = *(const float4*)&BI[r][td * 4];
#pragma unroll
      for (int i = 0; i < 4; ++i)
#pragma unroll
        for (int j = 0; j < 4; ++j) {
          pr[i][j] += ar[i] * br[j] + ai[i] * bi[j];
          pi[i][j] += ai[i] * br[j] - ar[i] * bi[j];
        }
    }
    const float sc = scale[f];
#pragma unroll
    for (int i = 0; i < 4; ++i) {
      const int e = te * 4 + i;
      ushort4 o;
      float w0 = (HR[e][td * 4 + 0] * pr[i][0] - HI[e][td * 4 + 0] * pi[i][0]) * sc;
      float w1 = (HR[e][td * 4 + 1] * pr[i][1] - HI[e][td * 4 + 1] * pi[i][1]) * sc;
      float w2 = (HR[e][td * 4 + 2] * pr[i][2] - HI[e][td * 4 + 2] * pi[i][2]) * sc;
      float w3 = (HR[e][td * 4 + 3] * pr[i][3] - HI[e][td * 4 + 3] * pi[i][3]) * sc;
      o.x = f2bf(w0); o.y = f2bf(w1); o.z = f2bf(w2); o.w = f2bf(w3);
      *(ushort4*)&W[((size_t)f * DD + e0 + e) * DD + d0 + td * 4] = o;
    }
  }
}

// ---------------- rmsnorm: h = bf16(x * rsqrt(mean(x^2)+eps) * w) ----------------
__global__ __launch_bounds__(256) void k_rmsnorm(const float* __restrict__ x,
                                                 const float* __restrict__ w,
                                                 unsigned short* __restrict__ h) {
  const int row = blockIdx.x, tid = threadIdx.x;
  const float4* xr = (const float4*)(x + (size_t)row * DD);
  const float4 a = xr[tid], b = xr[tid + 256];
  float s = a.x * a.x + a.y * a.y + a.z * a.z + a.w * a.w +
            b.x * b.x + b.y * b.y + b.z * b.z + b.w * b.w;
#pragma unroll
  for (int m = 32; m; m >>= 1) s += __shfl_xor(s, m);
  __shared__ float part[4];
  if ((tid & 63) == 0) part[tid >> 6] = s;
  __syncthreads();
  const float inv = rsqrtf((part[0] + part[1] + part[2] + part[3]) * (1.f / DD) + EPS_F);
  const float4* wr = (const float4*)w;
  const float4 w0 = wr[tid], w1 = wr[tid + 256];
  ushort4 o0, o1;
  o0.x = f2bf(a.x * inv * w0.x); o0.y = f2bf(a.y * inv * w0.y);
  o0.z = f2bf(a.z * inv * w0.z); o0.w = f2bf(a.w * inv * w0.w);
  o1.x = f2bf(b.x * inv * w1.x); o1.y = f2bf(b.y * inv * w1.y);
  o1.z = f2bf(b.z * inv * w1.z); o1.w = f2bf(b.w * inv * w1.w);
  ushort4* hd = (ushort4*)(h + (size_t)row * DD);
  hd[tid] = o0;
  hd[tid + 256] = o1;
}

// ---------------- GEMM: out[t][n] (+)= act( sum_k A[t][k]*B[n][k] ) ----------------
// A: [M][2048] bf16, B: [N][2048] bf16 (B^T layout). 128x128 tile, BK=32, 4 waves.
// ACT: 0 = C += v (residual), 1 = C += silu(v), 2 = C = v (store)
template <int ACT>
__global__ __launch_bounds__(256) void k_gemm(const unsigned short* __restrict__ A,
                                              const unsigned short* __restrict__ B,
                                              float* __restrict__ C, int ldc) {
  __shared__ unsigned short lsA[2][4096];
  __shared__ unsigned short lsB[2][4096];
  const int tid = threadIdx.x;
  const int lane = tid & 63, wave = tid >> 6;
  const int wm = wave >> 1, wn = wave & 1;
  const int t0 = blockIdx.x * 128, n0 = blockIdx.y * 128;
  const unsigned short* Ab = A + (size_t)t0 * DD;
  const unsigned short* Bb = B + (size_t)n0 * DD;
  const int srow = tid >> 2, scol = (tid & 3) * 8;

  f32x4 acc[4][4];
#pragma unroll
  for (int i = 0; i < 4; ++i)
#pragma unroll
    for (int j = 0; j < 4; ++j) acc[i][j] = (f32x4){0.f, 0.f, 0.f, 0.f};

  const int fr = lane & 15, fk = (lane >> 4) * 8;
  const int aoff = (wm * 64 + fr) * 32 + fk;
  const int boff = (wn * 64 + fr) * 32 + fk;

#define STAGE(buf, kt)                                                              \
  {                                                                                 \
    const int kb = (kt) * 32 + scol;                                                \
    gload_lds16(Ab + (size_t)srow * DD + kb,        &lsA[buf][tid * 8]);            \
    gload_lds16(Ab + (size_t)(srow + 64) * DD + kb, &lsA[buf][2048 + tid * 8]);     \
    gload_lds16(Bb + (size_t)srow * DD + kb,        &lsB[buf][tid * 8]);            \
    gload_lds16(Bb + (size_t)(srow + 64) * DD + kb, &lsB[buf][2048 + tid * 8]);     \
  }

  STAGE(0, 0);
  __syncthreads();
  for (int kt = 0; kt < 64; ++kt) {
    const int cur = kt & 1;
    if (kt < 63) STAGE(cur ^ 1, kt + 1);
    bf16x8 af[4], bg[4];
#pragma unroll
    for (int i = 0; i < 4; ++i) {
      af[i] = *(const bf16x8*)&lsA[cur][aoff + i * 16 * 32];
      bg[i] = *(const bf16x8*)&lsB[cur][boff + i * 16 * 32];
    }
#pragma unroll
    for (int mi = 0; mi < 4; ++mi)
#pragma unroll
      for (int ni = 0; ni < 4; ++ni)
        acc[mi][ni] = __builtin_amdgcn_mfma_f32_16x16x32_bf16(af[mi], bg[ni],
                                                              acc[mi][ni], 0, 0, 0);
    __syncthreads();
  }
#undef STAGE

  const int orow = t0 + wm * 64 + (lane >> 4) * 4;
  const int ocol = n0 + wn * 64 + (lane & 15);
#pragma unroll
  for (int mi = 0; mi < 4; ++mi)
#pragma unroll
    for (int ni = 0; ni < 4; ++ni)
#pragma unroll
      for (int j = 0; j < 4; ++j) {
        const size_t idx = (size_t)(orow + mi * 16 + j) * ldc + (ocol + ni * 16);
        const float v = acc[mi][ni][j];
        if (ACT == 0)      C[idx] += v;
        else if (ACT == 1) C[idx] += v / (1.f + __expf(-v));
        else               C[idx] = v;
      }
}

// ---------------- f32 -> bf16 bulk convert ----------------
__global__ void k_cvt(const float* __restrict__ in, unsigned short* __restrict__ out, int n4) {
  int i = blockIdx.x * blockDim.x + threadIdx.x;
  const int stride = gridDim.x * blockDim.x;
  for (; i < n4; i += stride) {
    const float4 v = ((const float4*)in)[i];
    ushort4 o;
    o.x = f2bf(v.x); o.y = f2bf(v.y); o.z = f2bf(v.z); o.w = f2bf(v.w);
    ((ushort4*)out)[i] = o;
  }
}

extern "C" void kernel_launch(void* const* d_in, const int* in_sizes, int n_in,
                              void* d_out, int out_size, void* d_ws, size_t ws_size,
                              hipStream_t stream) {
  (void)in_sizes; (void)n_in; (void)out_size; (void)ws_size;
  const int* tokens = (const int*)d_in[0];
  const float* hr = (const float*)d_in[1];
  const float* hi = (const float*)d_in[2];
  const float* kar = (const float*)d_in[3];
  const float* kai = (const float*)d_in[4];
  const float* kbr = (const float*)d_in[5];
  const float* kbi = (const float*)d_in[6];
  const float* lscale = (const float*)d_in[7];
  const float* norm_w = (const float*)d_in[8];
  const float* embed = (const float*)d_in[9];
  const float* lm = (const float*)d_in[10];
  const float* fnw = (const float*)d_in[11];
  float* out = (float*)d_out;
  char* ws = (char*)d_ws;

  // ws layout: W bf16 [24][2048][2048] @0 (201326592 B); h bf16 [4096][2048] after.
  // lm_bf16 overlays W (dead after last layer). x (f32, 33.5MB) lives in d_out:
  // it is dead before the final GEMM overwrites all of d_out.
  unsigned short* W = (unsigned short*)ws;
  unsigned short* h = (unsigned short*)(ws + 201326592);
  unsigned short* lmb = W;
  float* x = out;

  k_gather<<<NROWS, 256, 0, stream>>>(tokens, embed, x);
  k_wrec<<<dim3(32, 32), 256, 0, stream>>>(hr, hi, kar, kai, kbr, kbi, lscale, W);
  for (int l = 0; l < 12; ++l) {
    k_rmsnorm<<<NROWS, 256, 0, stream>>>(x, norm_w + (size_t)l * 2 * DD, h);
    k_gemm<0><<<dim3(32, 16), 256, 0, stream>>>(h, W + (size_t)(2 * l) * DD * DD, x, DD);
    k_rmsnorm<<<NROWS, 256, 0, stream>>>(x, norm_w + (size_t)l * 2 * DD + DD, h);
    k_gemm<1><<<dim3(32, 16), 256, 0, stream>>>(h, W + (size_t)(2 * l + 1) * DD * DD, x, DD);
  }
  k_rmsnorm<<<NROWS, 256, 0, stream>>>(x, fnw, h);
  k_cvt<<<2048, 256, 0, stream>>>(lm, lmb, VOCAB_N * DD / 4);
  k_gemm<2><<<dim3(32, 250), 256, 0, stream>>>(h, lmb, out, VOCAB_N);
}